// Round 4
// baseline (673.787 us; speedup 1.0000x reference)
//
#include <hip/hip_runtime.h>
#include <hip/hip_bf16.h>

typedef __attribute__((ext_vector_type(8))) short short8;
typedef __attribute__((ext_vector_type(4))) float float4v;

#define NB 4
#define NT 2048
#define NC 1024
#define NH 16
#define ND 64

__device__ __forceinline__ unsigned short f2bf(float f) {
    union { float f; unsigned int u; } v; v.f = f;
    unsigned int x = v.u;
    unsigned int r = (x + 0x7fffu + ((x >> 16) & 1u)) >> 16;
    return (unsigned short)r;
}

// fp32 -> bf16 (RNE) canonicalization, 8 elements/thread.
__global__ void canon_bf16(const float* __restrict__ src,
                           unsigned short* __restrict__ dst, int n)
{
    const int i = (blockIdx.x * blockDim.x + threadIdx.x) * 8;
    if (i >= n) return;
    float4v a = *(const float4v*)&src[i];
    float4v b = *(const float4v*)&src[i + 4];
    short8 o;
    o[0] = (short)f2bf(a[0]); o[1] = (short)f2bf(a[1]);
    o[2] = (short)f2bf(a[2]); o[3] = (short)f2bf(a[3]);
    o[4] = (short)f2bf(b[0]); o[5] = (short)f2bf(b[1]);
    o[6] = (short)f2bf(b[2]); o[7] = (short)f2bf(b[3]);
    *(short8*)&dst[i] = o;
}

// ---------------------------------------------------------------------------
// C[M,N] = A[M,K] * B[N,K]^T  (bf16 in, fp32 accum).
// Block: 256 threads (4 waves), tile 128x128, BK=32, global_load_lds width-16.
// MODE 0: epilogue scatters qkv (bf16) into q[B,H,T,D], k[B,H,T,D], vt[B,H,D,T]
// MODE 1: epilogue writes C row-major [M,1024] as FLOAT32 to `of`
// ---------------------------------------------------------------------------
template<int MODE>
__global__ __launch_bounds__(256)
void gemm_nt(const unsigned short* __restrict__ A,
             const unsigned short* __restrict__ Bm,
             unsigned short* __restrict__ o0,
             unsigned short* __restrict__ o1,
             unsigned short* __restrict__ o2,
             float* __restrict__ of,
             int K)
{
    __shared__ __align__(16) unsigned short As[128 * 32];
    __shared__ __align__(16) unsigned short Bs[128 * 32];
    const int t = threadIdx.x;
    const int w = t >> 6, lane = t & 63;
    const int quad = lane >> 4, l16 = lane & 15;
    const int wr = w >> 1, wc = w & 1;
    const int rowBase = blockIdx.y * 128;
    const int colBase = blockIdx.x * 128;

    float4v acc[4][4];
#pragma unroll
    for (int i = 0; i < 4; i++)
#pragma unroll
        for (int j = 0; j < 4; j++) acc[i][j] = (float4v){0.f, 0.f, 0.f, 0.f};

    const unsigned short* Ag = A + (size_t)(rowBase + w * 16 + (lane >> 2)) * K + (lane & 3) * 8;
    const unsigned short* Bg = Bm + (size_t)(colBase + w * 16 + (lane >> 2)) * K + (lane & 3) * 8;
    const int steps = K >> 5;

    for (int kt = 0; kt < steps; ++kt) {
        __syncthreads();
#pragma unroll
        for (int c = 0; c < 2; ++c) {
            __builtin_amdgcn_global_load_lds(
                (const __attribute__((address_space(1))) unsigned int*)(Ag + (size_t)c * 64 * K + kt * 32),
                (__attribute__((address_space(3))) unsigned int*)(&As[(c * 256 + w * 64) * 8]),
                16, 0, 0);
            __builtin_amdgcn_global_load_lds(
                (const __attribute__((address_space(1))) unsigned int*)(Bg + (size_t)c * 64 * K + kt * 32),
                (__attribute__((address_space(3))) unsigned int*)(&Bs[(c * 256 + w * 64) * 8]),
                16, 0, 0);
        }
        asm volatile("s_waitcnt vmcnt(0)" ::: "memory");
        __syncthreads();
        short8 af[4], bf[4];
#pragma unroll
        for (int i = 0; i < 4; i++)
            af[i] = *(const short8*)&As[(wr * 64 + i * 16 + l16) * 32 + quad * 8];
#pragma unroll
        for (int j = 0; j < 4; j++)
            bf[j] = *(const short8*)&Bs[(wc * 64 + j * 16 + l16) * 32 + quad * 8];
#pragma unroll
        for (int i = 0; i < 4; i++)
#pragma unroll
            for (int j = 0; j < 4; j++)
                acc[i][j] = __builtin_amdgcn_mfma_f32_16x16x32_bf16(af[i], bf[j], acc[i][j], 0, 0, 0);
    }

    // C/D layout: col = lane&15, row = quad*4 + r  (m89/m91-verified)
#pragma unroll
    for (int i = 0; i < 4; i++) {
        const int growb = rowBase + wr * 64 + i * 16 + quad * 4;
#pragma unroll
        for (int j = 0; j < 4; j++) {
            const int gcol = colBase + wc * 64 + j * 16 + l16;
#pragma unroll
            for (int r = 0; r < 4; r++) {
                const float vv = acc[i][j][r];
                const int gr = growb + r;
                if (MODE == 0) {
                    const unsigned short bv = f2bf(vv);
                    const int part = gcol >> 10;
                    const int rem = gcol & 1023;
                    const int h = rem >> 6, d = rem & 63;
                    const int b = gr >> 11, tt = gr & 2047;
                    const size_t bh = (size_t)(b * NH + h);
                    if (part == 0)      o0[(bh * NT + tt) * ND + d] = bv;
                    else if (part == 1) o1[(bh * NT + tt) * ND + d] = bv;
                    else                o2[(bh * ND + d) * NT + tt] = bv;
                } else {
                    of[(size_t)gr * NC + gcol] = vv;   // fp32 output
                }
            }
        }
    }
}

// ---------------------------------------------------------------------------
// Flash attention: block = 4 waves, each wave owns 16 queries of one (b,h).
// Block-uniform key-tile trip count; P C-layout -> A-layout via barrier-
// protected LDS round-trip (m120-verified pattern).
// ---------------------------------------------------------------------------
__global__ __launch_bounds__(256)
void attn_fused(const unsigned short* __restrict__ Q,
                const unsigned short* __restrict__ Kb,
                const unsigned short* __restrict__ Vt,
                unsigned short* __restrict__ att)
{
    const int bh = blockIdx.y;
    const int b = bh >> 4, h = bh & 15;
    const int t = threadIdx.x;
    const int w = t >> 6, lane = t & 63;
    const int quad = lane >> 4, l16 = lane & 15;
    const int qb = blockIdx.x * 64 + w * 16;

    __shared__ __align__(16) unsigned short Pl[4][16 * 32];

    short8 qf[2];
#pragma unroll
    for (int s = 0; s < 2; s++)
        qf[s] = *(const short8*)&Q[((size_t)bh * NT + qb + l16) * ND + s * 32 + quad * 8];

    float4v o[4];
#pragma unroll
    for (int jd = 0; jd < 4; jd++) o[jd] = (float4v){0.f, 0.f, 0.f, 0.f};
    float m_r[4], l_r[4];
#pragma unroll
    for (int r = 0; r < 4; r++) { m_r[r] = -1e30f; l_r[r] = 0.f; }

    const int nkt = ((blockIdx.x * 64 + 63) >> 5) + 1;
    for (int kt = 0; kt < nkt; ++kt) {
        const int kb = kt * 32;
        float4v s0 = (float4v){0.f, 0.f, 0.f, 0.f};
        float4v s1 = (float4v){0.f, 0.f, 0.f, 0.f};
#pragma unroll
        for (int s = 0; s < 2; s++) {
            short8 kf0 = *(const short8*)&Kb[((size_t)bh * NT + kb + l16) * ND + s * 32 + quad * 8];
            short8 kf1 = *(const short8*)&Kb[((size_t)bh * NT + kb + 16 + l16) * ND + s * 32 + quad * 8];
            s0 = __builtin_amdgcn_mfma_f32_16x16x32_bf16(qf[s], kf0, s0, 0, 0, 0);
            s1 = __builtin_amdgcn_mfma_f32_16x16x32_bf16(qf[s], kf1, s1, 0, 0, 0);
        }
        const int key0 = kb + l16, key1 = kb + 16 + l16;
        float p0[4], p1[4], alpha[4];
#pragma unroll
        for (int r = 0; r < 4; r++) {
            const int qq = qb + quad * 4 + r;
            float a = s0[r] * 0.125f;   // 1/sqrt(64)
            float c = s1[r] * 0.125f;
            if (key0 > qq) a = -1e30f;
            if (key1 > qq) c = -1e30f;
            float tm = fmaxf(a, c);
#pragma unroll
            for (int off = 1; off < 16; off <<= 1)
                tm = fmaxf(tm, __shfl_xor(tm, off));
            const float mnew = fmaxf(m_r[r], tm);
            alpha[r] = __expf(m_r[r] - mnew);
            const float e0 = __expf(a - mnew);
            const float e1 = __expf(c - mnew);
            p0[r] = e0; p1[r] = e1;
            float rs = e0 + e1;
#pragma unroll
            for (int off = 1; off < 16; off <<= 1)
                rs += __shfl_xor(rs, off);
            l_r[r] = l_r[r] * alpha[r] + rs;
            m_r[r] = mnew;
        }
#pragma unroll
        for (int jd = 0; jd < 4; jd++)
#pragma unroll
            for (int r = 0; r < 4; r++) o[jd][r] *= alpha[r];

        __syncthreads();
#pragma unroll
        for (int r = 0; r < 4; r++) {
            Pl[w][(quad * 4 + r) * 32 + l16]      = f2bf(p0[r]);
            Pl[w][(quad * 4 + r) * 32 + 16 + l16] = f2bf(p1[r]);
        }
        __syncthreads();
        const short8 pf = *(const short8*)&Pl[w][l16 * 32 + quad * 8];
#pragma unroll
        for (int jd = 0; jd < 4; jd++) {
            short8 vf = *(const short8*)&Vt[((size_t)bh * ND + jd * 16 + l16) * NT + kb + quad * 8];
            o[jd] = __builtin_amdgcn_mfma_f32_16x16x32_bf16(pf, vf, o[jd], 0, 0, 0);
        }
    }

    float rl[4];
#pragma unroll
    for (int r = 0; r < 4; r++) rl[r] = 1.0f / l_r[r];
#pragma unroll
    for (int jd = 0; jd < 4; jd++)
#pragma unroll
        for (int r = 0; r < 4; r++) {
            const int qq = qb + quad * 4 + r;
            att[((size_t)b * NT + qq) * NC + h * ND + jd * 16 + l16] = f2bf(o[jd][r] * rl[r]);
        }
}

extern "C" void kernel_launch(void* const* d_in, const int* in_sizes, int n_in,
                              void* d_out, int out_size, void* d_ws, size_t ws_size,
                              hipStream_t stream) {
    const float* x_raw     = (const float*)d_in[0];
    // d_in[1] = causal mask, reconstructed analytically (triu k=1) -> unused
    const float* w_qkv_raw = (const float*)d_in[2];
    const float* w_out_raw = (const float*)d_in[3];
    float* outp = (float*)d_out;   // reference output dtype = float32

    // workspace layout (bf16 elements)
    unsigned short* base = (unsigned short*)d_ws;
    const int n_x  = NB * NT * NC;        // 8,388,608
    const int n_wq = 3 * NC * NC;         // 3,145,728
    const int n_wo = NC * NC;             // 1,048,576
    const size_t tsz = (size_t)NB * NH * NT * ND;  // 8,388,608
    unsigned short* xb    = base;
    unsigned short* wqb   = xb + n_x;
    unsigned short* wob   = wqb + n_wq;
    unsigned short* qbuf  = wob + n_wo;
    unsigned short* kbuf  = qbuf + tsz;
    unsigned short* vtbuf = kbuf + tsz;
    unsigned short* attb  = xb;           // alias: x dead after QKV GEMM

    canon_bf16<<<n_x  / (256 * 8), 256, 0, stream>>>(x_raw,     xb,  n_x);
    canon_bf16<<<n_wq / (256 * 8), 256, 0, stream>>>(w_qkv_raw, wqb, n_wq);
    canon_bf16<<<n_wo / (256 * 8), 256, 0, stream>>>(w_out_raw, wob, n_wo);

    // QKV projection: M=8192, N=3072, K=1024
    gemm_nt<0><<<dim3(3072 / 128, (NB * NT) / 128), 256, 0, stream>>>(
        xb, wqb, qbuf, kbuf, vtbuf, nullptr, NC);
    // Fused causal attention (writes attb = xb region; xb no longer needed)
    attn_fused<<<dim3(NT / 64, NB * NH), 256, 0, stream>>>(qbuf, kbuf, vtbuf, attb);
    // Output projection: M=8192, N=1024, K=1024 -> fp32 out
    gemm_nt<1><<<dim3(NC / 128, (NB * NT) / 128), 256, 0, stream>>>(
        attb, wob, nullptr, nullptr, nullptr, outp, NC);
}

// Round 5
// 498.264 us; speedup vs baseline: 1.3523x; 1.3523x over previous
//
#include <hip/hip_runtime.h>
#include <hip/hip_bf16.h>

typedef __attribute__((ext_vector_type(8))) short short8;
typedef __attribute__((ext_vector_type(4))) float float4v;
typedef __attribute__((ext_vector_type(2))) unsigned int uint2v;

#define NB 4
#define NT 2048
#define NC 1024
#define NH 16
#define ND 64

__device__ __forceinline__ unsigned short f2bf(float f) {
    union { float f; unsigned int u; } v; v.f = f;
    unsigned int x = v.u;
    unsigned int r = (x + 0x7fffu + ((x >> 16) & 1u)) >> 16;
    return (unsigned short)r;
}

__device__ __forceinline__ unsigned int fbits(float f) {
    union { float f; unsigned int u; } v; v.f = f;
    return v.u;
}

// fp32 -> bf16 (RNE) canonicalization, 8 elements/thread.
__global__ void canon_bf16(const float* __restrict__ src,
                           unsigned short* __restrict__ dst, int n)
{
    const int i = (blockIdx.x * blockDim.x + threadIdx.x) * 8;
    if (i >= n) return;
    float4v a = *(const float4v*)&src[i];
    float4v b = *(const float4v*)&src[i + 4];
    short8 o;
    o[0] = (short)f2bf(a[0]); o[1] = (short)f2bf(a[1]);
    o[2] = (short)f2bf(a[2]); o[3] = (short)f2bf(a[3]);
    o[4] = (short)f2bf(b[0]); o[5] = (short)f2bf(b[1]);
    o[6] = (short)f2bf(b[2]); o[7] = (short)f2bf(b[3]);
    *(short8*)&dst[i] = o;
}

// ---------------------------------------------------------------------------
// C[M,N] = A[M,K] * B[N,K]^T  (bf16 in, fp32 accum).  (unchanged from R4)
// MODE 0: epilogue scatters qkv (bf16) into q[B,H,T,D], k[B,H,T,D], vt[B,H,D,T]
// MODE 1: epilogue writes C row-major [M,1024] as FLOAT32 to `of`
// ---------------------------------------------------------------------------
template<int MODE>
__global__ __launch_bounds__(256)
void gemm_nt(const unsigned short* __restrict__ A,
             const unsigned short* __restrict__ Bm,
             unsigned short* __restrict__ o0,
             unsigned short* __restrict__ o1,
             unsigned short* __restrict__ o2,
             float* __restrict__ of,
             int K)
{
    __shared__ __align__(16) unsigned short As[128 * 32];
    __shared__ __align__(16) unsigned short Bs[128 * 32];
    const int t = threadIdx.x;
    const int w = t >> 6, lane = t & 63;
    const int quad = lane >> 4, l16 = lane & 15;
    const int wr = w >> 1, wc = w & 1;
    const int rowBase = blockIdx.y * 128;
    const int colBase = blockIdx.x * 128;

    float4v acc[4][4];
#pragma unroll
    for (int i = 0; i < 4; i++)
#pragma unroll
        for (int j = 0; j < 4; j++) acc[i][j] = (float4v){0.f, 0.f, 0.f, 0.f};

    const unsigned short* Ag = A + (size_t)(rowBase + w * 16 + (lane >> 2)) * K + (lane & 3) * 8;
    const unsigned short* Bg = Bm + (size_t)(colBase + w * 16 + (lane >> 2)) * K + (lane & 3) * 8;
    const int steps = K >> 5;

    for (int kt = 0; kt < steps; ++kt) {
        __syncthreads();
#pragma unroll
        for (int c = 0; c < 2; ++c) {
            __builtin_amdgcn_global_load_lds(
                (const __attribute__((address_space(1))) unsigned int*)(Ag + (size_t)c * 64 * K + kt * 32),
                (__attribute__((address_space(3))) unsigned int*)(&As[(c * 256 + w * 64) * 8]),
                16, 0, 0);
            __builtin_amdgcn_global_load_lds(
                (const __attribute__((address_space(1))) unsigned int*)(Bg + (size_t)c * 64 * K + kt * 32),
                (__attribute__((address_space(3))) unsigned int*)(&Bs[(c * 256 + w * 64) * 8]),
                16, 0, 0);
        }
        asm volatile("s_waitcnt vmcnt(0)" ::: "memory");
        __syncthreads();
        short8 af[4], bf[4];
#pragma unroll
        for (int i = 0; i < 4; i++)
            af[i] = *(const short8*)&As[(wr * 64 + i * 16 + l16) * 32 + quad * 8];
#pragma unroll
        for (int j = 0; j < 4; j++)
            bf[j] = *(const short8*)&Bs[(wc * 64 + j * 16 + l16) * 32 + quad * 8];
#pragma unroll
        for (int i = 0; i < 4; i++)
#pragma unroll
            for (int j = 0; j < 4; j++)
                acc[i][j] = __builtin_amdgcn_mfma_f32_16x16x32_bf16(af[i], bf[j], acc[i][j], 0, 0, 0);
    }

    // C/D layout: col = lane&15, row = quad*4 + r  (m89/m91-verified)
#pragma unroll
    for (int i = 0; i < 4; i++) {
        const int growb = rowBase + wr * 64 + i * 16 + quad * 4;
#pragma unroll
        for (int j = 0; j < 4; j++) {
            const int gcol = colBase + wc * 64 + j * 16 + l16;
#pragma unroll
            for (int r = 0; r < 4; r++) {
                const float vv = acc[i][j][r];
                const int gr = growb + r;
                if (MODE == 0) {
                    const unsigned short bv = f2bf(vv);
                    const int part = gcol >> 10;
                    const int rem = gcol & 1023;
                    const int h = rem >> 6, d = rem & 63;
                    const int b = gr >> 11, tt = gr & 2047;
                    const size_t bh = (size_t)(b * NH + h);
                    if (part == 0)      o0[(bh * NT + tt) * ND + d] = bv;
                    else if (part == 1) o1[(bh * NT + tt) * ND + d] = bv;
                    else                o2[(bh * ND + d) * NT + tt] = bv;
                } else {
                    of[(size_t)gr * NC + gcol] = vv;   // fp32 output
                }
            }
        }
    }
}

// ---------------------------------------------------------------------------
// Flash attention, barrier-free wave-autonomous version.
//  - Each wave owns 16 queries; computes S^T = K*Q^T (query = lane column) so
//    softmax reductions are in-lane + 2 cross-quad shuffles.
//  - O^T = V^T * P accumulated via MFMA (query stays lane-aligned).
//  - P C->B-operand layout via WAVE-PRIVATE LDS round-trip (no __syncthreads).
//  - Balanced query-tile mapping: wave w of block x handles tile
//    {x, 63-x, 64+x, 127-x}[w] -> per-block work is constant.
// ---------------------------------------------------------------------------
#define PSTR 40   // LDS row stride in shorts (80 B: 16B-aligned rows, low conflict)

__global__ __launch_bounds__(256)
void attn_fused(const unsigned short* __restrict__ Q,
                const unsigned short* __restrict__ Kb,
                const unsigned short* __restrict__ Vt,
                unsigned short* __restrict__ att)
{
    const int bh = blockIdx.y;
    const int b = bh >> 4, h = bh & 15;
    const int t = threadIdx.x;
    const int w = t >> 6, lane = t & 63;
    const int quad = lane >> 4, l16 = lane & 15;
    const int x = blockIdx.x;
    const int m_idx = (w == 0) ? x : (w == 1) ? (63 - x) : (w == 2) ? (64 + x) : (127 - x);
    const int qb = m_idx * 16;

    __shared__ __align__(16) unsigned short Pl[4][16 * PSTR];
    unsigned short* Pw = &Pl[w][0];

    short8 qf[2];
#pragma unroll
    for (int s = 0; s < 2; s++)
        qf[s] = *(const short8*)&Q[((size_t)bh * NT + qb + l16) * ND + s * 32 + quad * 8];

    float4v o[4];
#pragma unroll
    for (int jd = 0; jd < 4; jd++) o[jd] = (float4v){0.f, 0.f, 0.f, 0.f};
    float m_s = -1e30f, l_s = 0.f;
    const float sc = 0.125f;   // 1/sqrt(64)
    const int q_own = qb + l16;

    const int nkt = ((qb + 15) >> 5) + 1;   // per-wave causal trip count
    for (int kt = 0; kt < nkt; ++kt) {
        const int kb = kt * 32;
        // S^T: A = K-frag (m=key), B = Q-frag (n=query)
        float4v s0 = (float4v){0.f, 0.f, 0.f, 0.f};
        float4v s1 = (float4v){0.f, 0.f, 0.f, 0.f};
#pragma unroll
        for (int s = 0; s < 2; s++) {
            short8 kf0 = *(const short8*)&Kb[((size_t)bh * NT + kb + l16) * ND + s * 32 + quad * 8];
            short8 kf1 = *(const short8*)&Kb[((size_t)bh * NT + kb + 16 + l16) * ND + s * 32 + quad * 8];
            s0 = __builtin_amdgcn_mfma_f32_16x16x32_bf16(kf0, qf[s], s0, 0, 0, 0);
            s1 = __builtin_amdgcn_mfma_f32_16x16x32_bf16(kf1, qf[s], s1, 0, 0, 0);
        }
        // lane holds 8 scores of query q_own: keys kb+quad*4+r (s0), +16 (s1)
        float a[8];
#pragma unroll
        for (int r = 0; r < 4; r++) { a[r] = s0[r] * sc; a[4 + r] = s1[r] * sc; }
        if (kb + 31 > qb) {   // diagonal tile only (wave-uniform)
#pragma unroll
            for (int r = 0; r < 4; r++) {
                if (kb + quad * 4 + r > q_own)      a[r]     = -1e30f;
                if (kb + 16 + quad * 4 + r > q_own) a[4 + r] = -1e30f;
            }
        }
        // row max: in-lane over 8, then cross-quad (same l16 = same query)
        float tm = fmaxf(fmaxf(fmaxf(a[0], a[1]), fmaxf(a[2], a[3])),
                         fmaxf(fmaxf(a[4], a[5]), fmaxf(a[6], a[7])));
        tm = fmaxf(tm, __shfl_xor(tm, 16));
        tm = fmaxf(tm, __shfl_xor(tm, 32));
        const float mnew = fmaxf(m_s, tm);
        const float alpha = __expf(m_s - mnew);
        float e[8], rs = 0.f;
#pragma unroll
        for (int i = 0; i < 8; i++) { e[i] = __expf(a[i] - mnew); rs += e[i]; }
        rs += __shfl_xor(rs, 16);
        rs += __shfl_xor(rs, 32);
        l_s = l_s * alpha + rs;
        m_s = mnew;
#pragma unroll
        for (int jd = 0; jd < 4; jd++)
#pragma unroll
            for (int r = 0; r < 4; r++) o[jd][r] *= alpha;

        // P[q][key] -> wave-private LDS (bf16 truncation; P in [0,1])
        unsigned int dw0 = (fbits(e[1]) & 0xFFFF0000u) | (fbits(e[0]) >> 16);
        unsigned int dw1 = (fbits(e[3]) & 0xFFFF0000u) | (fbits(e[2]) >> 16);
        unsigned int dw2 = (fbits(e[5]) & 0xFFFF0000u) | (fbits(e[4]) >> 16);
        unsigned int dw3 = (fbits(e[7]) & 0xFFFF0000u) | (fbits(e[6]) >> 16);
        *(uint2v*)&Pw[l16 * PSTR + quad * 4]      = (uint2v){dw0, dw1};
        *(uint2v*)&Pw[l16 * PSTR + 16 + quad * 4] = (uint2v){dw2, dw3};
        asm volatile("s_waitcnt lgkmcnt(0)" ::: "memory");
        const short8 pf = *(const short8*)&Pw[l16 * PSTR + quad * 8];

        // O^T += V^T * P : A = Vt-frag (m=d), B = P-frag (n=query)
#pragma unroll
        for (int jd = 0; jd < 4; jd++) {
            short8 vf = *(const short8*)&Vt[((size_t)bh * ND + jd * 16 + l16) * NT + kb + quad * 8];
            o[jd] = __builtin_amdgcn_mfma_f32_16x16x32_bf16(vf, pf, o[jd], 0, 0, 0);
        }
    }

    // epilogue: lane's query = q_own; d = jd*16 + quad*4 + r
    const float rl = 1.0f / l_s;
    unsigned int* att32 = (unsigned int*)att;
#pragma unroll
    for (int jd = 0; jd < 4; jd++)
#pragma unroll
        for (int rp = 0; rp < 2; rp++) {
            const float v0 = o[jd][2 * rp] * rl;
            const float v1 = o[jd][2 * rp + 1] * rl;
            const size_t el = ((size_t)b * NT + q_own) * NC + h * ND + jd * 16 + quad * 4 + 2 * rp;
            att32[el >> 1] = (unsigned int)f2bf(v0) | ((unsigned int)f2bf(v1) << 16);
        }
}

extern "C" void kernel_launch(void* const* d_in, const int* in_sizes, int n_in,
                              void* d_out, int out_size, void* d_ws, size_t ws_size,
                              hipStream_t stream) {
    const float* x_raw     = (const float*)d_in[0];
    // d_in[1] = causal mask, reconstructed analytically (triu k=1) -> unused
    const float* w_qkv_raw = (const float*)d_in[2];
    const float* w_out_raw = (const float*)d_in[3];
    float* outp = (float*)d_out;   // reference output dtype = float32

    // workspace layout (bf16 elements)
    unsigned short* base = (unsigned short*)d_ws;
    const int n_x  = NB * NT * NC;        // 8,388,608
    const int n_wq = 3 * NC * NC;         // 3,145,728
    const int n_wo = NC * NC;             // 1,048,576
    const size_t tsz = (size_t)NB * NH * NT * ND;  // 8,388,608
    unsigned short* xb    = base;
    unsigned short* wqb   = xb + n_x;
    unsigned short* wob   = wqb + n_wq;
    unsigned short* qbuf  = wob + n_wo;
    unsigned short* kbuf  = qbuf + tsz;
    unsigned short* vtbuf = kbuf + tsz;
    unsigned short* attb  = xb;           // alias: x dead after QKV GEMM

    canon_bf16<<<n_x  / (256 * 8), 256, 0, stream>>>(x_raw,     xb,  n_x);
    canon_bf16<<<n_wq / (256 * 8), 256, 0, stream>>>(w_qkv_raw, wqb, n_wq);
    canon_bf16<<<n_wo / (256 * 8), 256, 0, stream>>>(w_out_raw, wob, n_wo);

    // QKV projection: M=8192, N=3072, K=1024
    gemm_nt<0><<<dim3(3072 / 128, (NB * NT) / 128), 256, 0, stream>>>(
        xb, wqb, qbuf, kbuf, vtbuf, nullptr, NC);
    // Fused causal attention (writes attb = xb region; xb no longer needed)
    attn_fused<<<dim3(NT / 64, NB * NH), 256, 0, stream>>>(qbuf, kbuf, vtbuf, attb);
    // Output projection: M=8192, N=1024, K=1024 -> fp32 out
    gemm_nt<1><<<dim3(NC / 128, (NB * NT) / 128), 256, 0, stream>>>(
        attb, wob, nullptr, nullptr, nullptr, outp, NC);
}

// Round 7
// 319.027 us; speedup vs baseline: 2.1120x; 1.5618x over previous
//
#include <hip/hip_runtime.h>
#include <hip/hip_bf16.h>

typedef __attribute__((ext_vector_type(8))) short short8;
typedef __attribute__((ext_vector_type(4))) float float4v;
typedef __attribute__((ext_vector_type(2))) unsigned int uint2v;

#define NB 4
#define NT 2048
#define NC 1024
#define NH 16
#define ND 64

__device__ __forceinline__ unsigned short f2bf(float f) {
    union { float f; unsigned int u; } v; v.f = f;
    unsigned int x = v.u;
    unsigned int r = (x + 0x7fffu + ((x >> 16) & 1u)) >> 16;
    return (unsigned short)r;
}

__device__ __forceinline__ unsigned int fbits(float f) {
    union { float f; unsigned int u; } v; v.f = f;
    return v.u;
}

// fp32 -> bf16 (RNE) canonicalization, 8 elements/thread.
__global__ void canon_bf16(const float* __restrict__ src,
                           unsigned short* __restrict__ dst, int n)
{
    const int i = (blockIdx.x * blockDim.x + threadIdx.x) * 8;
    if (i >= n) return;
    float4v a = *(const float4v*)&src[i];
    float4v b = *(const float4v*)&src[i + 4];
    short8 o;
    o[0] = (short)f2bf(a[0]); o[1] = (short)f2bf(a[1]);
    o[2] = (short)f2bf(a[2]); o[3] = (short)f2bf(a[3]);
    o[4] = (short)f2bf(b[0]); o[5] = (short)f2bf(b[1]);
    o[6] = (short)f2bf(b[2]); o[7] = (short)f2bf(b[3]);
    *(short8*)&dst[i] = o;
}

// ---------------------------------------------------------------------------
// C[M,N] = A[M,K] * B[N,K]^T  (bf16 in, fp32 accum).  (unchanged from R5)
// MODE 0: epilogue scatters qkv (bf16) into q[B,H,T,D], k[B,H,T,D], vt[B,H,D,T]
// MODE 1: epilogue writes C row-major [M,1024] as FLOAT32 to `of`
// ---------------------------------------------------------------------------
template<int MODE>
__global__ __launch_bounds__(256)
void gemm_nt(const unsigned short* __restrict__ A,
             const unsigned short* __restrict__ Bm,
             unsigned short* __restrict__ o0,
             unsigned short* __restrict__ o1,
             unsigned short* __restrict__ o2,
             float* __restrict__ of,
             int K)
{
    __shared__ __align__(16) unsigned short As[128 * 32];
    __shared__ __align__(16) unsigned short Bs[128 * 32];
    const int t = threadIdx.x;
    const int w = t >> 6, lane = t & 63;
    const int quad = lane >> 4, l16 = lane & 15;
    const int wr = w >> 1, wc = w & 1;
    const int rowBase = blockIdx.y * 128;
    const int colBase = blockIdx.x * 128;

    float4v acc[4][4];
#pragma unroll
    for (int i = 0; i < 4; i++)
#pragma unroll
        for (int j = 0; j < 4; j++) acc[i][j] = (float4v){0.f, 0.f, 0.f, 0.f};

    const unsigned short* Ag = A + (size_t)(rowBase + w * 16 + (lane >> 2)) * K + (lane & 3) * 8;
    const unsigned short* Bg = Bm + (size_t)(colBase + w * 16 + (lane >> 2)) * K + (lane & 3) * 8;
    const int steps = K >> 5;

    for (int kt = 0; kt < steps; ++kt) {
        __syncthreads();
#pragma unroll
        for (int c = 0; c < 2; ++c) {
            __builtin_amdgcn_global_load_lds(
                (const __attribute__((address_space(1))) unsigned int*)(Ag + (size_t)c * 64 * K + kt * 32),
                (__attribute__((address_space(3))) unsigned int*)(&As[(c * 256 + w * 64) * 8]),
                16, 0, 0);
            __builtin_amdgcn_global_load_lds(
                (const __attribute__((address_space(1))) unsigned int*)(Bg + (size_t)c * 64 * K + kt * 32),
                (__attribute__((address_space(3))) unsigned int*)(&Bs[(c * 256 + w * 64) * 8]),
                16, 0, 0);
        }
        asm volatile("s_waitcnt vmcnt(0)" ::: "memory");
        __syncthreads();
        short8 af[4], bf[4];
#pragma unroll
        for (int i = 0; i < 4; i++)
            af[i] = *(const short8*)&As[(wr * 64 + i * 16 + l16) * 32 + quad * 8];
#pragma unroll
        for (int j = 0; j < 4; j++)
            bf[j] = *(const short8*)&Bs[(wc * 64 + j * 16 + l16) * 32 + quad * 8];
#pragma unroll
        for (int i = 0; i < 4; i++)
#pragma unroll
            for (int j = 0; j < 4; j++)
                acc[i][j] = __builtin_amdgcn_mfma_f32_16x16x32_bf16(af[i], bf[j], acc[i][j], 0, 0, 0);
    }

    // C/D layout: col = lane&15, row = quad*4 + r  (m89/m91-verified)
#pragma unroll
    for (int i = 0; i < 4; i++) {
        const int growb = rowBase + wr * 64 + i * 16 + quad * 4;
#pragma unroll
        for (int j = 0; j < 4; j++) {
            const int gcol = colBase + wc * 64 + j * 16 + l16;
#pragma unroll
            for (int r = 0; r < 4; r++) {
                const float vv = acc[i][j][r];
                const int gr = growb + r;
                if (MODE == 0) {
                    const unsigned short bv = f2bf(vv);
                    const int part = gcol >> 10;
                    const int rem = gcol & 1023;
                    const int h = rem >> 6, d = rem & 63;
                    const int b = gr >> 11, tt = gr & 2047;
                    const size_t bh = (size_t)(b * NH + h);
                    if (part == 0)      o0[(bh * NT + tt) * ND + d] = bv;
                    else if (part == 1) o1[(bh * NT + tt) * ND + d] = bv;
                    else                o2[(bh * ND + d) * NT + tt] = bv;
                } else {
                    of[(size_t)gr * NC + gcol] = vv;   // fp32 output
                }
            }
        }
    }
}

// ---------------------------------------------------------------------------
// Flash attention, FA2-style block-cooperative (R6 structure, PSTR bug fixed):
//  - Block = 4 waves = 64 contiguous queries of one (b,h); K/V 64-key tiles
//    staged once into LDS (global_load_lds, XOR-swizzled layout) and shared.
//  - Perfect balance: block x handles Q-tile pair (x, 31-x) sequentially ->
//    every block exactly 33 key-iterations.
//  - Per wave: S^T = K*Q^T (query = lane column, softmax in-lane + 2 shuffles),
//    P via wave-private LDS round-trip (R5-validated), O^T = V^T*P.
// Swizzle: 16B chunk c of a 64x64 tile stores global (row=c>>3, col8=(c&7)^(row&7));
// element (row,col8) read at LDS short-offset row*64 + (col8^(row&7))*8.
// ---------------------------------------------------------------------------
#define PSTR 72   // P row stride in shorts: 64 keys + pad; 144 B (16B-aligned).
                  // R6 bug: PSTR=40 < 64 -> cross-wave LDS overflow.

__global__ __launch_bounds__(256)
void attn_fused(const unsigned short* __restrict__ Q,
                const unsigned short* __restrict__ Kb,
                const unsigned short* __restrict__ Vt,
                unsigned short* __restrict__ att)
{
    const int bh = blockIdx.y;
    const int b = bh >> 4, h = bh & 15;
    const int t = threadIdx.x;
    const int w = t >> 6, lane = t & 63;
    const int quad = lane >> 4, l16 = lane & 15;
    const int l8 = l16 & 7;

    __shared__ __align__(16) unsigned short Ks[64 * 64];
    __shared__ __align__(16) unsigned short Vs[64 * 64];
    __shared__ __align__(16) unsigned short Pl[4][16 * PSTR];
    unsigned short* Pw = &Pl[w][0];

    // staging source indices (swizzled column), shared by both 32-row halves
    const int srow = t >> 3;                       // 0..31
    const int scol = ((t & 7) ^ (srow & 7)) * 8;   // swizzled col in shorts

    const float sc = 0.125f;   // 1/sqrt(64)

    for (int phase = 0; phase < 2; ++phase) {
        const int qtile = (phase == 0) ? (int)blockIdx.x : 31 - (int)blockIdx.x;
        const int qb = qtile * 64 + w * 16;
        const int q_local = w * 16 + l16;          // query index within the 64-block
        const int q_own = qb + l16;

        short8 qf[2];
#pragma unroll
        for (int s = 0; s < 2; s++)
            qf[s] = *(const short8*)&Q[((size_t)bh * NT + qb + l16) * ND + s * 32 + quad * 8];

        float4v o[4];
#pragma unroll
        for (int jd = 0; jd < 4; jd++) o[jd] = (float4v){0.f, 0.f, 0.f, 0.f};
        float m_s = -1e30f, l_s = 0.f;

        const int nkt = qtile + 1;
        for (int kt = 0; kt < nkt; ++kt) {
            const int kb = kt * 64;
            // ---- stage K/V tile (8 KB each) into LDS, swizzled ----
            // LDS dest: wave-uniform base; HW scatters lane i at base + i*16B.
#pragma unroll
            for (int p = 0; p < 2; ++p) {
                __builtin_amdgcn_global_load_lds(
                    (const __attribute__((address_space(1))) unsigned int*)
                        (Kb + ((size_t)bh * NT + kb + p * 32 + srow) * ND + scol),
                    (__attribute__((address_space(3))) unsigned int*)(&Ks[(p * 256 + w * 64) * 8]),
                    16, 0, 0);
                __builtin_amdgcn_global_load_lds(
                    (const __attribute__((address_space(1))) unsigned int*)
                        (Vt + ((size_t)bh * ND + p * 32 + srow) * NT + kb + scol),
                    (__attribute__((address_space(3))) unsigned int*)(&Vs[(p * 256 + w * 64) * 8]),
                    16, 0, 0);
            }
            asm volatile("s_waitcnt vmcnt(0)" ::: "memory");
            __syncthreads();

            // ---- S^T = K * Q^T : 4 key-fragments x K=64 ----
            float4v sacc[4];
#pragma unroll
            for (int f = 0; f < 4; f++) sacc[f] = (float4v){0.f, 0.f, 0.f, 0.f};
#pragma unroll
            for (int f = 0; f < 4; f++)
#pragma unroll
                for (int s = 0; s < 2; s++) {
                    short8 kf = *(const short8*)&Ks[(f * 16 + l16) * 64 + (((s * 4 + quad) ^ l8) * 8)];
                    sacc[f] = __builtin_amdgcn_mfma_f32_16x16x32_bf16(kf, qf[s], sacc[f], 0, 0, 0);
                }

            // lane holds 16 scores of query q_own: keys kb + f*16 + quad*4 + r
            float a[16];
#pragma unroll
            for (int f = 0; f < 4; f++)
#pragma unroll
                for (int r = 0; r < 4; r++) a[f * 4 + r] = sacc[f][r] * sc;
            if (kt == qtile) {   // diagonal tile (wave-uniform)
#pragma unroll
                for (int f = 0; f < 4; f++)
#pragma unroll
                    for (int r = 0; r < 4; r++)
                        if (f * 16 + quad * 4 + r > q_local) a[f * 4 + r] = -1e30f;
            }
            // row max: in-lane 16 + cross-quad
            float tm = a[0];
#pragma unroll
            for (int i = 1; i < 16; i++) tm = fmaxf(tm, a[i]);
            tm = fmaxf(tm, __shfl_xor(tm, 16));
            tm = fmaxf(tm, __shfl_xor(tm, 32));
            const float mnew = fmaxf(m_s, tm);
            const float alpha = __expf(m_s - mnew);
            float e[16], rs = 0.f;
#pragma unroll
            for (int i = 0; i < 16; i++) { e[i] = __expf(a[i] - mnew); rs += e[i]; }
            rs += __shfl_xor(rs, 16);
            rs += __shfl_xor(rs, 32);
            l_s = l_s * alpha + rs;
            m_s = mnew;
#pragma unroll
            for (int jd = 0; jd < 4; jd++)
#pragma unroll
                for (int r = 0; r < 4; r++) o[jd][r] *= alpha;

            // P[q][key] -> wave-private LDS (bf16 truncation; P in [0,1])
#pragma unroll
            for (int f = 0; f < 4; f++) {
                unsigned int d0 = (fbits(e[f * 4 + 1]) & 0xFFFF0000u) | (fbits(e[f * 4 + 0]) >> 16);
                unsigned int d1 = (fbits(e[f * 4 + 3]) & 0xFFFF0000u) | (fbits(e[f * 4 + 2]) >> 16);
                *(uint2v*)&Pw[l16 * PSTR + f * 16 + quad * 4] = (uint2v){d0, d1};
            }
            asm volatile("s_waitcnt lgkmcnt(0)" ::: "memory");
            const short8 pf0 = *(const short8*)&Pw[l16 * PSTR + quad * 8];
            const short8 pf1 = *(const short8*)&Pw[l16 * PSTR + 32 + quad * 8];

            // O^T += V^T * P
#pragma unroll
            for (int jd = 0; jd < 4; jd++) {
                short8 vf0 = *(const short8*)&Vs[(jd * 16 + l16) * 64 + ((quad ^ l8) * 8)];
                short8 vf1 = *(const short8*)&Vs[(jd * 16 + l16) * 64 + (((4 + quad) ^ l8) * 8)];
                o[jd] = __builtin_amdgcn_mfma_f32_16x16x32_bf16(vf0, pf0, o[jd], 0, 0, 0);
                o[jd] = __builtin_amdgcn_mfma_f32_16x16x32_bf16(vf1, pf1, o[jd], 0, 0, 0);
            }
            __syncthreads();   // all waves done with Ks/Vs before next stage
        }

        // epilogue: lane's query = q_own; d = jd*16 + quad*4 + r
        const float rl = 1.0f / l_s;
        unsigned int* att32 = (unsigned int*)att;
#pragma unroll
        for (int jd = 0; jd < 4; jd++)
#pragma unroll
            for (int rp = 0; rp < 2; rp++) {
                const float v0 = o[jd][2 * rp] * rl;
                const float v1 = o[jd][2 * rp + 1] * rl;
                const size_t el = ((size_t)b * NT + q_own) * NC + h * ND + jd * 16 + quad * 4 + 2 * rp;
                att32[el >> 1] = (unsigned int)f2bf(v0) | ((unsigned int)f2bf(v1) << 16);
            }
    }
}

extern "C" void kernel_launch(void* const* d_in, const int* in_sizes, int n_in,
                              void* d_out, int out_size, void* d_ws, size_t ws_size,
                              hipStream_t stream) {
    const float* x_raw     = (const float*)d_in[0];
    // d_in[1] = causal mask, reconstructed analytically (triu k=1) -> unused
    const float* w_qkv_raw = (const float*)d_in[2];
    const float* w_out_raw = (const float*)d_in[3];
    float* outp = (float*)d_out;   // reference output dtype = float32

    // workspace layout (bf16 elements)
    unsigned short* base = (unsigned short*)d_ws;
    const int n_x  = NB * NT * NC;        // 8,388,608
    const int n_wq = 3 * NC * NC;         // 3,145,728
    const int n_wo = NC * NC;             // 1,048,576
    const size_t tsz = (size_t)NB * NH * NT * ND;  // 8,388,608
    unsigned short* xb    = base;
    unsigned short* wqb   = xb + n_x;
    unsigned short* wob   = wqb + n_wq;
    unsigned short* qbuf  = wob + n_wo;
    unsigned short* kbuf  = qbuf + tsz;
    unsigned short* vtbuf = kbuf + tsz;
    unsigned short* attb  = xb;           // alias: x dead after QKV GEMM

    canon_bf16<<<n_x  / (256 * 8), 256, 0, stream>>>(x_raw,     xb,  n_x);
    canon_bf16<<<n_wq / (256 * 8), 256, 0, stream>>>(w_qkv_raw, wqb, n_wq);
    canon_bf16<<<n_wo / (256 * 8), 256, 0, stream>>>(w_out_raw, wob, n_wo);

    // QKV projection: M=8192, N=3072, K=1024
    gemm_nt<0><<<dim3(3072 / 128, (NB * NT) / 128), 256, 0, stream>>>(
        xb, wqb, qbuf, kbuf, vtbuf, nullptr, NC);
    // Fused causal attention: block x handles Q-tile pair (x, 31-x)
    attn_fused<<<dim3(16, NB * NH), 256, 0, stream>>>(qbuf, kbuf, vtbuf, attb);
    // Output projection: M=8192, N=1024, K=1024 -> fp32 out
    gemm_nt<1><<<dim3(NC / 128, (NB * NT) / 128), 256, 0, stream>>>(
        attb, wob, nullptr, nullptr, nullptr, outp, NC);
}

// Round 8
// 305.168 us; speedup vs baseline: 2.2079x; 1.0454x over previous
//
#include <hip/hip_runtime.h>
#include <hip/hip_bf16.h>

typedef __attribute__((ext_vector_type(8))) short short8;
typedef __attribute__((ext_vector_type(4))) float float4v;
typedef __attribute__((ext_vector_type(2))) unsigned int uint2v;

#define NB 4
#define NT 2048
#define NC 1024
#define NH 16
#define ND 64

__device__ __forceinline__ unsigned short f2bf(float f) {
    union { float f; unsigned int u; } v; v.f = f;
    unsigned int x = v.u;
    unsigned int r = (x + 0x7fffu + ((x >> 16) & 1u)) >> 16;
    return (unsigned short)r;
}

__device__ __forceinline__ unsigned int fbits(float f) {
    union { float f; unsigned int u; } v; v.f = f;
    return v.u;
}

// fp32 -> bf16 (RNE) canonicalization, 8 elements/thread.
__global__ void canon_bf16(const float* __restrict__ src,
                           unsigned short* __restrict__ dst, int n)
{
    const int i = (blockIdx.x * blockDim.x + threadIdx.x) * 8;
    if (i >= n) return;
    float4v a = *(const float4v*)&src[i];
    float4v b = *(const float4v*)&src[i + 4];
    short8 o;
    o[0] = (short)f2bf(a[0]); o[1] = (short)f2bf(a[1]);
    o[2] = (short)f2bf(a[2]); o[3] = (short)f2bf(a[3]);
    o[4] = (short)f2bf(b[0]); o[5] = (short)f2bf(b[1]);
    o[6] = (short)f2bf(b[2]); o[7] = (short)f2bf(b[3]);
    *(short8*)&dst[i] = o;
}

// ---------------------------------------------------------------------------
// C[M,N] = A[M,K] * B[N,K]^T  (bf16 in, fp32 accum).
// R8: BK=64 K-loop (steps = K/64) + source-side XOR swizzle (R7-attn-validated):
//   16B chunk c of a 128x64 tile stages global (row=c>>3, col8=(c&7)^(row&7));
//   element (row,col8) is read at LDS short-offset row*64 + (col8^(row&7))*8.
//   -> fragment ds_read_b128 bank aliasing drops 8-way -> 2-way (free),
//      barrier/drain count halves vs BK=32.
// MODE 0: epilogue scatters qkv (bf16) into q[B,H,T,D] (PRE-SCALED by 1/8),
//         k[B,H,T,D], vt[B,H,D,T]
// MODE 1: epilogue writes C row-major [M,1024] as FLOAT32 to `of`
// ---------------------------------------------------------------------------
template<int MODE>
__global__ __launch_bounds__(256)
void gemm_nt(const unsigned short* __restrict__ A,
             const unsigned short* __restrict__ Bm,
             unsigned short* __restrict__ o0,
             unsigned short* __restrict__ o1,
             unsigned short* __restrict__ o2,
             float* __restrict__ of,
             int K)
{
    __shared__ __align__(16) unsigned short As[128 * 64];
    __shared__ __align__(16) unsigned short Bs[128 * 64];
    const int t = threadIdx.x;
    const int w = t >> 6, lane = t & 63;
    const int quad = lane >> 4, l16 = lane & 15;
    const int l8 = l16 & 7;
    const int wr = w >> 1, wc = w & 1;
    const int rowBase = blockIdx.y * 128;
    const int colBase = blockIdx.x * 128;

    float4v acc[4][4];
#pragma unroll
    for (int i = 0; i < 4; i++)
#pragma unroll
        for (int j = 0; j < 4; j++) acc[i][j] = (float4v){0.f, 0.f, 0.f, 0.f};

    // staging: chunk c = q*256 + t covers tile row q*32 + (t>>3),
    // source col8 = (t&7) ^ (row&7)  (row&7 == (t>>3)&7)
    const int srow8 = t >> 3;                          // 0..31
    const int scol = ((t & 7) ^ (srow8 & 7)) * 8;      // swizzled col, shorts
    const unsigned short* Ag = A + (size_t)(rowBase + srow8) * K + scol;
    const unsigned short* Bg = Bm + (size_t)(colBase + srow8) * K + scol;
    const int steps = K >> 6;

    for (int kt = 0; kt < steps; ++kt) {
        __syncthreads();   // WAR: all waves done reading previous tile
#pragma unroll
        for (int q = 0; q < 4; ++q) {
            __builtin_amdgcn_global_load_lds(
                (const __attribute__((address_space(1))) unsigned int*)(Ag + (size_t)q * 32 * K + kt * 64),
                (__attribute__((address_space(3))) unsigned int*)(&As[(q * 256 + w * 64) * 8]),
                16, 0, 0);
            __builtin_amdgcn_global_load_lds(
                (const __attribute__((address_space(1))) unsigned int*)(Bg + (size_t)q * 32 * K + kt * 64),
                (__attribute__((address_space(3))) unsigned int*)(&Bs[(q * 256 + w * 64) * 8]),
                16, 0, 0);
        }
        asm volatile("s_waitcnt vmcnt(0)" ::: "memory");
        __syncthreads();
#pragma unroll
        for (int ks = 0; ks < 2; ++ks) {
            const int co = ((ks * 4 + quad) ^ l8) * 8;
            short8 af[4], bf[4];
#pragma unroll
            for (int i = 0; i < 4; i++)
                af[i] = *(const short8*)&As[(wr * 64 + i * 16 + l16) * 64 + co];
#pragma unroll
            for (int j = 0; j < 4; j++)
                bf[j] = *(const short8*)&Bs[(wc * 64 + j * 16 + l16) * 64 + co];
#pragma unroll
            for (int i = 0; i < 4; i++)
#pragma unroll
                for (int j = 0; j < 4; j++)
                    acc[i][j] = __builtin_amdgcn_mfma_f32_16x16x32_bf16(af[i], bf[j], acc[i][j], 0, 0, 0);
        }
    }

    // C/D layout: col = lane&15, row = quad*4 + r  (m89/m91-verified)
#pragma unroll
    for (int i = 0; i < 4; i++) {
        const int growb = rowBase + wr * 64 + i * 16 + quad * 4;
#pragma unroll
        for (int j = 0; j < 4; j++) {
            const int gcol = colBase + wc * 64 + j * 16 + l16;
#pragma unroll
            for (int r = 0; r < 4; r++) {
                const int gr = growb + r;
                if (MODE == 0) {
                    // Q part pre-scaled by 1/sqrt(64) so attn skips the multiply
                    const float vv = (gcol < 1024) ? acc[i][j][r] * 0.125f : acc[i][j][r];
                    const unsigned short bv = f2bf(vv);
                    const int part = gcol >> 10;
                    const int rem = gcol & 1023;
                    const int h = rem >> 6, d = rem & 63;
                    const int b = gr >> 11, tt = gr & 2047;
                    const size_t bh = (size_t)(b * NH + h);
                    if (part == 0)      o0[(bh * NT + tt) * ND + d] = bv;
                    else if (part == 1) o1[(bh * NT + tt) * ND + d] = bv;
                    else                o2[(bh * ND + d) * NT + tt] = bv;
                } else {
                    of[(size_t)gr * NC + gcol] = acc[i][j][r];   // fp32 output
                }
            }
        }
    }
}

// ---------------------------------------------------------------------------
// Flash attention, FA2-style block-cooperative (R7-validated):
//  - Block = 4 waves = 64 contiguous queries of one (b,h); K/V 64-key tiles
//    staged once into LDS (global_load_lds, XOR-swizzled layout) and shared.
//  - Perfect balance: block x handles Q-tile pair (x, 31-x) sequentially ->
//    every block exactly 33 key-iterations.
//  - Per wave: S^T = K*Q^T (query = lane column, softmax in-lane + 2 shuffles),
//    P via wave-private LDS round-trip, O^T = V^T*P.
//  - Q is pre-scaled by 1/sqrt(64) in the QKV GEMM epilogue (R8).
// ---------------------------------------------------------------------------
#define PSTR 72   // P row stride in shorts: 64 keys + pad; 144 B (16B-aligned)

__global__ __launch_bounds__(256)
void attn_fused(const unsigned short* __restrict__ Q,
                const unsigned short* __restrict__ Kb,
                const unsigned short* __restrict__ Vt,
                unsigned short* __restrict__ att)
{
    const int bh = blockIdx.y;
    const int b = bh >> 4, h = bh & 15;
    const int t = threadIdx.x;
    const int w = t >> 6, lane = t & 63;
    const int quad = lane >> 4, l16 = lane & 15;
    const int l8 = l16 & 7;

    __shared__ __align__(16) unsigned short Ks[64 * 64];
    __shared__ __align__(16) unsigned short Vs[64 * 64];
    __shared__ __align__(16) unsigned short Pl[4][16 * PSTR];
    unsigned short* Pw = &Pl[w][0];

    // staging source indices (swizzled column), shared by both 32-row halves
    const int srow = t >> 3;                       // 0..31
    const int scol = ((t & 7) ^ (srow & 7)) * 8;   // swizzled col in shorts

    for (int phase = 0; phase < 2; ++phase) {
        const int qtile = (phase == 0) ? (int)blockIdx.x : 31 - (int)blockIdx.x;
        const int qb = qtile * 64 + w * 16;
        const int q_local = w * 16 + l16;          // query index within the 64-block
        const int q_own = qb + l16;

        short8 qf[2];
#pragma unroll
        for (int s = 0; s < 2; s++)
            qf[s] = *(const short8*)&Q[((size_t)bh * NT + qb + l16) * ND + s * 32 + quad * 8];

        float4v o[4];
#pragma unroll
        for (int jd = 0; jd < 4; jd++) o[jd] = (float4v){0.f, 0.f, 0.f, 0.f};
        float m_s = -1e30f, l_s = 0.f;

        const int nkt = qtile + 1;
        for (int kt = 0; kt < nkt; ++kt) {
            const int kb = kt * 64;
            // ---- stage K/V tile (8 KB each) into LDS, swizzled ----
#pragma unroll
            for (int p = 0; p < 2; ++p) {
                __builtin_amdgcn_global_load_lds(
                    (const __attribute__((address_space(1))) unsigned int*)
                        (Kb + ((size_t)bh * NT + kb + p * 32 + srow) * ND + scol),
                    (__attribute__((address_space(3))) unsigned int*)(&Ks[(p * 256 + w * 64) * 8]),
                    16, 0, 0);
                __builtin_amdgcn_global_load_lds(
                    (const __attribute__((address_space(1))) unsigned int*)
                        (Vt + ((size_t)bh * ND + p * 32 + srow) * NT + kb + scol),
                    (__attribute__((address_space(3))) unsigned int*)(&Vs[(p * 256 + w * 64) * 8]),
                    16, 0, 0);
            }
            asm volatile("s_waitcnt vmcnt(0)" ::: "memory");
            __syncthreads();

            // ---- S^T = K * Q^T : 4 key-fragments x K=64 ----
            float4v sacc[4];
#pragma unroll
            for (int f = 0; f < 4; f++) sacc[f] = (float4v){0.f, 0.f, 0.f, 0.f};
#pragma unroll
            for (int f = 0; f < 4; f++)
#pragma unroll
                for (int s = 0; s < 2; s++) {
                    short8 kf = *(const short8*)&Ks[(f * 16 + l16) * 64 + (((s * 4 + quad) ^ l8) * 8)];
                    sacc[f] = __builtin_amdgcn_mfma_f32_16x16x32_bf16(kf, qf[s], sacc[f], 0, 0, 0);
                }

            // lane holds 16 scores of query q_own: keys kb + f*16 + quad*4 + r
            float a[16];
#pragma unroll
            for (int f = 0; f < 4; f++)
#pragma unroll
                for (int r = 0; r < 4; r++) a[f * 4 + r] = sacc[f][r];
            if (kt == qtile) {   // diagonal tile (wave-uniform)
#pragma unroll
                for (int f = 0; f < 4; f++)
#pragma unroll
                    for (int r = 0; r < 4; r++)
                        if (f * 16 + quad * 4 + r > q_local) a[f * 4 + r] = -1e30f;
            }
            // row max: in-lane 16 + cross-quad
            float tm = a[0];
#pragma unroll
            for (int i = 1; i < 16; i++) tm = fmaxf(tm, a[i]);
            tm = fmaxf(tm, __shfl_xor(tm, 16));
            tm = fmaxf(tm, __shfl_xor(tm, 32));
            const float mnew = fmaxf(m_s, tm);
            const float alpha = __expf(m_s - mnew);
            float e[16], rs = 0.f;
#pragma unroll
            for (int i = 0; i < 16; i++) { e[i] = __expf(a[i] - mnew); rs += e[i]; }
            rs += __shfl_xor(rs, 16);
            rs += __shfl_xor(rs, 32);
            l_s = l_s * alpha + rs;
            m_s = mnew;
#pragma unroll
            for (int jd = 0; jd < 4; jd++)
#pragma unroll
                for (int r = 0; r < 4; r++) o[jd][r] *= alpha;

            // P[q][key] -> wave-private LDS (bf16 truncation; P in [0,1])
#pragma unroll
            for (int f = 0; f < 4; f++) {
                unsigned int d0 = (fbits(e[f * 4 + 1]) & 0xFFFF0000u) | (fbits(e[f * 4 + 0]) >> 16);
                unsigned int d1 = (fbits(e[f * 4 + 3]) & 0xFFFF0000u) | (fbits(e[f * 4 + 2]) >> 16);
                *(uint2v*)&Pw[l16 * PSTR + f * 16 + quad * 4] = (uint2v){d0, d1};
            }
            asm volatile("s_waitcnt lgkmcnt(0)" ::: "memory");
            const short8 pf0 = *(const short8*)&Pw[l16 * PSTR + quad * 8];
            const short8 pf1 = *(const short8*)&Pw[l16 * PSTR + 32 + quad * 8];

            // O^T += V^T * P
#pragma unroll
            for (int jd = 0; jd < 4; jd++) {
                short8 vf0 = *(const short8*)&Vs[(jd * 16 + l16) * 64 + ((quad ^ l8) * 8)];
                short8 vf1 = *(const short8*)&Vs[(jd * 16 + l16) * 64 + (((4 + quad) ^ l8) * 8)];
                o[jd] = __builtin_amdgcn_mfma_f32_16x16x32_bf16(vf0, pf0, o[jd], 0, 0, 0);
                o[jd] = __builtin_amdgcn_mfma_f32_16x16x32_bf16(vf1, pf1, o[jd], 0, 0, 0);
            }
            __syncthreads();   // all waves done with Ks/Vs before next stage
        }

        // epilogue: lane's query = q_own; d = jd*16 + quad*4 + r
        const float rl = 1.0f / l_s;
        unsigned int* att32 = (unsigned int*)att;
#pragma unroll
        for (int jd = 0; jd < 4; jd++)
#pragma unroll
            for (int rp = 0; rp < 2; rp++) {
                const float v0 = o[jd][2 * rp] * rl;
                const float v1 = o[jd][2 * rp + 1] * rl;
                const size_t el = ((size_t)b * NT + q_own) * NC + h * ND + jd * 16 + quad * 4 + 2 * rp;
                att32[el >> 1] = (unsigned int)f2bf(v0) | ((unsigned int)f2bf(v1) << 16);
            }
    }
}

extern "C" void kernel_launch(void* const* d_in, const int* in_sizes, int n_in,
                              void* d_out, int out_size, void* d_ws, size_t ws_size,
                              hipStream_t stream) {
    const float* x_raw     = (const float*)d_in[0];
    // d_in[1] = causal mask, reconstructed analytically (triu k=1) -> unused
    const float* w_qkv_raw = (const float*)d_in[2];
    const float* w_out_raw = (const float*)d_in[3];
    float* outp = (float*)d_out;   // reference output dtype = float32

    // workspace layout (bf16 elements)
    unsigned short* base = (unsigned short*)d_ws;
    const int n_x  = NB * NT * NC;        // 8,388,608
    const int n_wq = 3 * NC * NC;         // 3,145,728
    const int n_wo = NC * NC;             // 1,048,576
    const size_t tsz = (size_t)NB * NH * NT * ND;  // 8,388,608
    unsigned short* xb    = base;
    unsigned short* wqb   = xb + n_x;
    unsigned short* wob   = wqb + n_wq;
    unsigned short* qbuf  = wob + n_wo;
    unsigned short* kbuf  = qbuf + tsz;
    unsigned short* vtbuf = kbuf + tsz;
    unsigned short* attb  = xb;           // alias: x dead after QKV GEMM

    canon_bf16<<<n_x  / (256 * 8), 256, 0, stream>>>(x_raw,     xb,  n_x);
    canon_bf16<<<n_wq / (256 * 8), 256, 0, stream>>>(w_qkv_raw, wqb, n_wq);
    canon_bf16<<<n_wo / (256 * 8), 256, 0, stream>>>(w_out_raw, wob, n_wo);

    // QKV projection: M=8192, N=3072, K=1024
    gemm_nt<0><<<dim3(3072 / 128, (NB * NT) / 128), 256, 0, stream>>>(
        xb, wqb, qbuf, kbuf, vtbuf, nullptr, NC);
    // Fused causal attention: block x handles Q-tile pair (x, 31-x)
    attn_fused<<<dim3(16, NB * NH), 256, 0, stream>>>(qbuf, kbuf, vtbuf, attb);
    // Output projection: M=8192, N=1024, K=1024 -> fp32 out
    gemm_nt<1><<<dim3(NC / 128, (NB * NT) / 128), 256, 0, stream>>>(
        attb, wob, nullptr, nullptr, nullptr, outp, NC);
}